// Round 1
// baseline (218.808 us; speedup 1.0000x reference)
//
#include <hip/hip_runtime.h>
#include <hip/hip_fp16.h>

// Trilinear sampler: im [B,H,W,D,C] f32, coords [B,N,3] f32 (y,x,z), out [B,N,C] f32.
// B=2, H=W=D=128, C=2, N=H*W*D.
//
// R8: LDS-staged repack.
//   R7 post-mortem: repack was TA-request-bound (2 overlapping 16B loads +
//   1 store per thread x 8.4M threads = 25M requests ~= 41us at ~1 req/cyc/CU),
//   not byte-bound (168 MB ~= 28us). R8 stages each block's 4 voxel rows into
//   LDS with ONE coalesced 16B load per thread, builds chunks from LDS, keeps
//   R7's single full-line-coalesced nt store (chunk id == tid).
//   Global requests 25M -> 16.8M.
// Sample pass unchanged: pinned at the random 64B-line fill floor
// (FETCH = N x 64B = 280 MB at ~3.5 TB/s; invariant across R1/R2/R4/R5).
//
// R9 (this round): identical resubmit — R8's bench run died with a broker
// "container failed twice" infra error (no counters, no verdict). Baseline
// re-establish + counter capture before any further edit.

constexpr int Hc = 128, Wc = 128, Dc = 128;
constexpr int Npts = Hc * Wc * Dc;                 // 2^21 points per batch
constexpr int CELLS = 1 << 21;                     // 128^3 cell records per batch
constexpr size_t REC_BYTES = (size_t)2 * CELLS * 32;   // 134,217,728 (both batches)
constexpr int PTS_PER_THREAD = 4;
constexpr int NTHREADS = 2 * Npts / PTS_PER_THREAD;
constexpr int BLOCK = 256;
constexpr int NCHUNKS = 1 << 23;                   // 2 batches * CELLS * 2 halves

typedef float nfloat4 __attribute__((ext_vector_type(4)));   // native vec for nt builtins

// 16-byte payload with only 8-byte alignment guarantee (fallback path)
struct __attribute__((packed, aligned(8))) f4u { float x, y, z, w; };

// ---------------- repack: im (fp32) -> per-cell 2x2x2x2ch fp16 records ----------------
// record layout (32B): half0 = y plane [x z, x z+1, x1 z, x1 z+1],
//                      half1 = y1 plane [same], each half2 = (c0,c1).
// Block = 256 chunks = 128 cells = one full z-row at fixed (b,y,x).
__global__ __launch_bounds__(BLOCK)
void TrilinearSampler_34059090658011_repack(const float* __restrict__ im,
                                            nfloat4* __restrict__ rec) {
    __shared__ __align__(16) float2 srow[4][128];          // rows: (y,x),(y,x1),(y1,x),(y1,x1)

    const int tid     = threadIdx.x;
    const int gchunk0 = blockIdx.x * BLOCK;                // block's first chunk (256-aligned)
    const int b       = gchunk0 >> 22;                     // 2^22 chunks per batch
    const int cell0   = (gchunk0 & ((1 << 22) - 1)) >> 1;  // first cell (z=0)
    const int x = (cell0 >> 7) & 127;
    const int y = cell0 >> 14;

    const float* __restrict__ imb = im + ((size_t)b << 22);   // 2^21 cells * 2ch floats

    // ---- stage: thread loads one 16B piece; lane-consecutive within each row ----
    const int y1v = ::min(y + 1, 127);
    const int x1v = ::min(x + 1, 127);
    const int r = tid >> 6;                                // row 0..3
    const int p = tid & 63;                                // 16B piece within row
    const int rowv = (r == 0) ? (y   * 128 + x  )
                   : (r == 1) ? (y   * 128 + x1v)
                   : (r == 2) ? (y1v * 128 + x  )
                   :            (y1v * 128 + x1v);
    const nfloat4 v = *reinterpret_cast<const nfloat4*>(imb + (size_t)rowv * 256 + p * 4);
    reinterpret_cast<nfloat4*>(&srow[r][0])[p] = v;
    __syncthreads();

    // ---- assemble: thread builds one 16B chunk (cell z, half h) ----
    const int h  = tid & 1;                                // 0: y plane, 1: y1 plane
    const int z  = tid >> 1;                               // cell z
    const int zb = ::min(z, 126);                          // z=127 cell never sampled
    const int ra = h ? 2 : 0;                              // (yh, x)
    const int rx = h ? 3 : 1;                              // (yh, x1)
    const float2 a0 = srow[ra][zb], a1 = srow[ra][zb + 1];
    const float2 b0 = srow[rx][zb], b1 = srow[rx][zb + 1];

    union { __half2 hh[4]; nfloat4 f; } u;
    u.hh[0] = __floats2half2_rn(a0.x, a0.y);               // (yh, x,  z)
    u.hh[1] = __floats2half2_rn(a1.x, a1.y);               // (yh, x,  z+1)
    u.hh[2] = __floats2half2_rn(b0.x, b0.y);               // (yh, x1, z)
    u.hh[3] = __floats2half2_rn(b1.x, b1.y);               // (yh, x1, z+1)

    // chunk address == global chunk id -> lane i stores base+16*i: full-line stream
    __builtin_nontemporal_store(u.f, rec + gchunk0 + tid);
}

// ---------------- sample pass: one 32B record (one 64B line) per point ----------------
__global__ __launch_bounds__(BLOCK)
void TrilinearSampler_34059090658011_sample(const nfloat4* __restrict__ rec,
                                            const float* __restrict__ coords,
                                            float* __restrict__ out) {
    const int t = blockIdx.x * BLOCK + threadIdx.x;        // one thread = 4 points

    const nfloat4* __restrict__ c4 = reinterpret_cast<const nfloat4*>(coords);
    const nfloat4 ca = __builtin_nontemporal_load(&c4[3 * t + 0]);
    const nfloat4 cb = __builtin_nontemporal_load(&c4[3 * t + 1]);
    const nfloat4 cc = __builtin_nontemporal_load(&c4[3 * t + 2]);

    const int b = (t * PTS_PER_THREAD) >> 21;              // wave-uniform
    const nfloat4* __restrict__ rb = rec + ((size_t)b << 22);   // CELLS*2 nfloat4/batch

    const float ys[4] = {ca.x, ca.w, cb.z, cc.y};
    const float xs[4] = {ca.y, cb.x, cb.w, cc.z};
    const float zs[4] = {ca.z, cb.y, cc.x, cc.w};

    // phase 1: cells + weights
    int   cidx[4];
    float dxs[4], dys[4], dzs[4];
#pragma unroll
    for (int i = 0; i < 4; ++i) {
        const float x = xs[i] + 1.0f;
        const float y = ys[i] + 1.0f;
        const float z = zs[i] + 1.0f;
        const int x0 = (int)floorf(x);
        const int y0 = (int)floorf(y);
        const int z0 = (int)floorf(z);
        dxs[i] = (float)(x0 + 1) - x;                      // interior guaranteed
        dys[i] = (float)(y0 + 1) - y;
        dzs[i] = (float)(z0 + 1) - z;
        const int ix0 = ::min(::max(x0 - 1, 0), Wc - 2);
        const int iy0 = ::min(::max(y0 - 1, 0), Hc - 2);
        const int izb = ::min(::max(z0 - 1, 0), Dc - 2);
        cidx[i] = ((iy0 << 7) | ix0) << 7 | izb;
    }

    // phase 2: 8 loads (2 per point, same 64B line)
    nfloat4 lo[4], hi[4];
#pragma unroll
    for (int i = 0; i < 4; ++i) {
        lo[i] = rb[(size_t)cidx[i] * 2 + 0];
        hi[i] = rb[(size_t)cidx[i] * 2 + 1];
    }

    // phase 3: combine
    float res[8];
#pragma unroll
    for (int i = 0; i < 4; ++i) {
        const __half2* h = reinterpret_cast<const __half2*>(&lo[i]);   // y0 plane
        const __half2* g = reinterpret_cast<const __half2*>(&hi[i]);   // y1 plane
        const float2 f0 = __half22float2(h[0]);   // y0 x0 z0
        const float2 f1 = __half22float2(h[1]);   // y0 x0 z1
        const float2 f2 = __half22float2(h[2]);   // y0 x1 z0
        const float2 f3 = __half22float2(h[3]);   // y0 x1 z1
        const float2 f4 = __half22float2(g[0]);   // y1 x0 z0
        const float2 f5 = __half22float2(g[1]);   // y1 x0 z1
        const float2 f6 = __half22float2(g[2]);   // y1 x1 z0
        const float2 f7 = __half22float2(g[3]);   // y1 x1 z1

        const float dx = dxs[i], dy = dys[i], dz = dzs[i];
        const float w00 = dy * dx,          w01 = dy * (1.0f - dx);
        const float w10 = (1.0f - dy) * dx, w11 = (1.0f - dy) * (1.0f - dx);
        const float wz0 = dz, wz1 = 1.0f - dz;

        const float a0 = w00 * f0.x + w01 * f2.x + w10 * f4.x + w11 * f6.x;  // z0, c0
        const float b0 = w00 * f0.y + w01 * f2.y + w10 * f4.y + w11 * f6.y;  // z0, c1
        const float a1 = w00 * f1.x + w01 * f3.x + w10 * f5.x + w11 * f7.x;  // z1, c0
        const float b1 = w00 * f1.y + w01 * f3.y + w10 * f5.y + w11 * f7.y;  // z1, c1

        res[2 * i + 0] = wz0 * a0 + wz1 * a1;
        res[2 * i + 1] = wz0 * b0 + wz1 * b1;
    }

    nfloat4* __restrict__ o4 = reinterpret_cast<nfloat4*>(out);
    const nfloat4 r0 = {res[0], res[1], res[2], res[3]};
    const nfloat4 r1 = {res[4], res[5], res[6], res[7]};
    __builtin_nontemporal_store(r0, &o4[2 * t + 0]);
    __builtin_nontemporal_store(r1, &o4[2 * t + 1]);
}

// ---------------- fallback (direct fp32 path, both batches) ----------------
__global__ __launch_bounds__(BLOCK)
void TrilinearSampler_34059090658011_kernel(const float* __restrict__ im,
                                            const float* __restrict__ coords,
                                            float* __restrict__ out) {
    const int t = blockIdx.x * BLOCK + threadIdx.x;

    const float4* __restrict__ c4 = reinterpret_cast<const float4*>(coords);
    const float4 ca = c4[3 * t + 0];
    const float4 cb = c4[3 * t + 1];
    const float4 cc = c4[3 * t + 2];

    const int b = (t * PTS_PER_THREAD) >> 21;
    const char* __restrict__ imb =
        reinterpret_cast<const char*>(im) + (size_t)b * (size_t)Npts * 8u;

    const float ys[4] = {ca.x, ca.w, cb.z, cc.y};
    const float xs[4] = {ca.y, cb.x, cb.w, cc.z};
    const float zs[4] = {ca.z, cb.y, cc.x, cc.w};

    int   off[16];
    float w00[4], w01[4], w10[4], w11[4], wz0[4], wz1[4];
#pragma unroll
    for (int i = 0; i < 4; ++i) {
        const float x = xs[i] + 1.0f;
        const float y = ys[i] + 1.0f;
        const float z = zs[i] + 1.0f;
        const int x0 = (int)floorf(x);
        const int y0 = (int)floorf(y);
        const int z0 = (int)floorf(z);
        const float dx = (float)(x0 + 1) - x;
        const float dy = (float)(y0 + 1) - y;
        const float dz = (float)(z0 + 1) - z;
        const int ix0 = ::min(::max(x0 - 1, 0), Wc - 2);
        const int iy0 = ::min(::max(y0 - 1, 0), Hc - 2);
        const int izb = ::min(::max(z0 - 1, 0), Dc - 2);
        w00[i] = dx * dy;
        w01[i] = dx * (1.0f - dy);
        w10[i] = (1.0f - dx) * dy;
        w11[i] = (1.0f - dx) * (1.0f - dy);
        wz0[i] = dz;
        wz1[i] = 1.0f - dz;
        const int r00 = ((iy0 * Wc + ix0) * Dc + izb) * 8;
        off[4 * i + 0] = r00;
        off[4 * i + 1] = r00 + Wc * Dc * 8;
        off[4 * i + 2] = r00 + Dc * 8;
        off[4 * i + 3] = r00 + (Wc + 1) * Dc * 8;
    }

    f4u g[16];
#pragma unroll
    for (int j = 0; j < 16; ++j)
        g[j] = *reinterpret_cast<const f4u*>(imb + off[j]);

    float res[8];
#pragma unroll
    for (int i = 0; i < 4; ++i) {
        const f4u g00 = g[4 * i + 0];
        const f4u g01 = g[4 * i + 1];
        const f4u g10 = g[4 * i + 2];
        const f4u g11 = g[4 * i + 3];
        const float az0c0 = w00[i] * g00.x + w01[i] * g01.x + w10[i] * g10.x + w11[i] * g11.x;
        const float az0c1 = w00[i] * g00.y + w01[i] * g01.y + w10[i] * g10.y + w11[i] * g11.y;
        const float az1c0 = w00[i] * g00.z + w01[i] * g01.z + w10[i] * g10.z + w11[i] * g11.z;
        const float az1c1 = w00[i] * g00.w + w01[i] * g01.w + w10[i] * g10.w + w11[i] * g11.w;
        res[2 * i + 0] = wz0[i] * az0c0 + wz1[i] * az1c0;
        res[2 * i + 1] = wz0[i] * az0c1 + wz1[i] * az1c1;
    }

    float4* __restrict__ o4 = reinterpret_cast<float4*>(out);
    o4[2 * t + 0] = make_float4(res[0], res[1], res[2], res[3]);
    o4[2 * t + 1] = make_float4(res[4], res[5], res[6], res[7]);
}

extern "C" void kernel_launch(void* const* d_in, const int* in_sizes, int n_in,
                              void* d_out, int out_size, void* d_ws, size_t ws_size,
                              hipStream_t stream) {
    const float* im     = (const float*)d_in[0];
    const float* coords = (const float*)d_in[1];
    float* out          = (float*)d_out;

    if (ws_size >= REC_BYTES) {
        nfloat4* rec = (nfloat4*)d_ws;
        TrilinearSampler_34059090658011_repack<<<dim3(NCHUNKS / BLOCK), dim3(BLOCK), 0, stream>>>(im, rec);
        TrilinearSampler_34059090658011_sample<<<dim3(NTHREADS / BLOCK), dim3(BLOCK), 0, stream>>>(rec, coords, out);
    } else {
        TrilinearSampler_34059090658011_kernel<<<dim3(NTHREADS / BLOCK), dim3(BLOCK), 0, stream>>>(im, coords, out);
    }
}

// Round 2
// 216.027 us; speedup vs baseline: 1.0129x; 1.0129x over previous
//
#include <hip/hip_runtime.h>
#include <hip/hip_fp16.h>

// Trilinear sampler: im [B,H,W,D,C] f32, coords [B,N,3] f32 (y,x,z), out [B,N,C] f32.
// B=2, H=W=D=128, C=2, N=H*W*D.
//
// R8: LDS-staged repack (requests 25M -> 16.8M). Sample: one random 32B record
//   (one 64B line) per point.
// R10 (this round): repack rec store nt -> PLAIN store.
//   R9 counters: sample = 92.2us, FETCH 280MB at 3.5 TB/s (44% of HBM peak),
//   VALUBusy 8%. rec (128 MiB) fits the 256 MiB Infinity Cache, so if records
//   were LLC-resident the random fills should beat 3.5 TB/s. Theory: the nt
//   store's no-allocate hint pushes rec out to HBM, and every sample fill
//   round-trips to HBM at the random-64B-granule rate (~44% of peak).
//   Plain store write-allocates -> rec stays LLC-resident for the sample pass.
//   Predict: sample 92 -> ~65-75us (FETCH unchanged, service rate up),
//   repack +0-5us, total 219 -> ~195-200us. If unchanged: 3.5 TB/s IS the
//   LLC random ceiling and sample is at its floor.

constexpr int Hc = 128, Wc = 128, Dc = 128;
constexpr int Npts = Hc * Wc * Dc;                 // 2^21 points per batch
constexpr int CELLS = 1 << 21;                     // 128^3 cell records per batch
constexpr size_t REC_BYTES = (size_t)2 * CELLS * 32;   // 134,217,728 (both batches)
constexpr int PTS_PER_THREAD = 4;
constexpr int NTHREADS = 2 * Npts / PTS_PER_THREAD;
constexpr int BLOCK = 256;
constexpr int NCHUNKS = 1 << 23;                   // 2 batches * CELLS * 2 halves

typedef float nfloat4 __attribute__((ext_vector_type(4)));   // native vec for nt builtins

// 16-byte payload with only 8-byte alignment guarantee (fallback path)
struct __attribute__((packed, aligned(8))) f4u { float x, y, z, w; };

// ---------------- repack: im (fp32) -> per-cell 2x2x2x2ch fp16 records ----------------
// record layout (32B): half0 = y plane [x z, x z+1, x1 z, x1 z+1],
//                      half1 = y1 plane [same], each half2 = (c0,c1).
// Block = 256 chunks = 128 cells = one full z-row at fixed (b,y,x).
__global__ __launch_bounds__(BLOCK)
void TrilinearSampler_34059090658011_repack(const float* __restrict__ im,
                                            nfloat4* __restrict__ rec) {
    __shared__ __align__(16) float2 srow[4][128];          // rows: (y,x),(y,x1),(y1,x),(y1,x1)

    const int tid     = threadIdx.x;
    const int gchunk0 = blockIdx.x * BLOCK;                // block's first chunk (256-aligned)
    const int b       = gchunk0 >> 22;                     // 2^22 chunks per batch
    const int cell0   = (gchunk0 & ((1 << 22) - 1)) >> 1;  // first cell (z=0)
    const int x = (cell0 >> 7) & 127;
    const int y = cell0 >> 14;

    const float* __restrict__ imb = im + ((size_t)b << 22);   // 2^21 cells * 2ch floats

    // ---- stage: thread loads one 16B piece; lane-consecutive within each row ----
    const int y1v = ::min(y + 1, 127);
    const int x1v = ::min(x + 1, 127);
    const int r = tid >> 6;                                // row 0..3
    const int p = tid & 63;                                // 16B piece within row
    const int rowv = (r == 0) ? (y   * 128 + x  )
                   : (r == 1) ? (y   * 128 + x1v)
                   : (r == 2) ? (y1v * 128 + x  )
                   :            (y1v * 128 + x1v);
    const nfloat4 v = *reinterpret_cast<const nfloat4*>(imb + (size_t)rowv * 256 + p * 4);
    reinterpret_cast<nfloat4*>(&srow[r][0])[p] = v;
    __syncthreads();

    // ---- assemble: thread builds one 16B chunk (cell z, half h) ----
    const int h  = tid & 1;                                // 0: y plane, 1: y1 plane
    const int z  = tid >> 1;                               // cell z
    const int zb = ::min(z, 126);                          // z=127 cell never sampled
    const int ra = h ? 2 : 0;                              // (yh, x)
    const int rx = h ? 3 : 1;                              // (yh, x1)
    const float2 a0 = srow[ra][zb], a1 = srow[ra][zb + 1];
    const float2 b0 = srow[rx][zb], b1 = srow[rx][zb + 1];

    union { __half2 hh[4]; nfloat4 f; } u;
    u.hh[0] = __floats2half2_rn(a0.x, a0.y);               // (yh, x,  z)
    u.hh[1] = __floats2half2_rn(a1.x, a1.y);               // (yh, x,  z+1)
    u.hh[2] = __floats2half2_rn(b0.x, b0.y);               // (yh, x1, z)
    u.hh[3] = __floats2half2_rn(b1.x, b1.y);               // (yh, x1, z+1)

    // chunk address == global chunk id -> lane i stores base+16*i: full-line stream.
    // R10: PLAIN store (write-allocate) so rec stays L2/LLC-resident for sample.
    rec[gchunk0 + tid] = u.f;
}

// ---------------- sample pass: one 32B record (one 64B line) per point ----------------
__global__ __launch_bounds__(BLOCK)
void TrilinearSampler_34059090658011_sample(const nfloat4* __restrict__ rec,
                                            const float* __restrict__ coords,
                                            float* __restrict__ out) {
    const int t = blockIdx.x * BLOCK + threadIdx.x;        // one thread = 4 points

    const nfloat4* __restrict__ c4 = reinterpret_cast<const nfloat4*>(coords);
    const nfloat4 ca = __builtin_nontemporal_load(&c4[3 * t + 0]);
    const nfloat4 cb = __builtin_nontemporal_load(&c4[3 * t + 1]);
    const nfloat4 cc = __builtin_nontemporal_load(&c4[3 * t + 2]);

    const int b = (t * PTS_PER_THREAD) >> 21;              // wave-uniform
    const nfloat4* __restrict__ rb = rec + ((size_t)b << 22);   // CELLS*2 nfloat4/batch

    const float ys[4] = {ca.x, ca.w, cb.z, cc.y};
    const float xs[4] = {ca.y, cb.x, cb.w, cc.z};
    const float zs[4] = {ca.z, cb.y, cc.x, cc.w};

    // phase 1: cells + weights
    int   cidx[4];
    float dxs[4], dys[4], dzs[4];
#pragma unroll
    for (int i = 0; i < 4; ++i) {
        const float x = xs[i] + 1.0f;
        const float y = ys[i] + 1.0f;
        const float z = zs[i] + 1.0f;
        const int x0 = (int)floorf(x);
        const int y0 = (int)floorf(y);
        const int z0 = (int)floorf(z);
        dxs[i] = (float)(x0 + 1) - x;                      // interior guaranteed
        dys[i] = (float)(y0 + 1) - y;
        dzs[i] = (float)(z0 + 1) - z;
        const int ix0 = ::min(::max(x0 - 1, 0), Wc - 2);
        const int iy0 = ::min(::max(y0 - 1, 0), Hc - 2);
        const int izb = ::min(::max(z0 - 1, 0), Dc - 2);
        cidx[i] = ((iy0 << 7) | ix0) << 7 | izb;
    }

    // phase 2: 8 loads (2 per point, same 64B line)
    nfloat4 lo[4], hi[4];
#pragma unroll
    for (int i = 0; i < 4; ++i) {
        lo[i] = rb[(size_t)cidx[i] * 2 + 0];
        hi[i] = rb[(size_t)cidx[i] * 2 + 1];
    }

    // phase 3: combine
    float res[8];
#pragma unroll
    for (int i = 0; i < 4; ++i) {
        const __half2* h = reinterpret_cast<const __half2*>(&lo[i]);   // y0 plane
        const __half2* g = reinterpret_cast<const __half2*>(&hi[i]);   // y1 plane
        const float2 f0 = __half22float2(h[0]);   // y0 x0 z0
        const float2 f1 = __half22float2(h[1]);   // y0 x0 z1
        const float2 f2 = __half22float2(h[2]);   // y0 x1 z0
        const float2 f3 = __half22float2(h[3]);   // y0 x1 z1
        const float2 f4 = __half22float2(g[0]);   // y1 x0 z0
        const float2 f5 = __half22float2(g[1]);   // y1 x0 z1
        const float2 f6 = __half22float2(g[2]);   // y1 x1 z0
        const float2 f7 = __half22float2(g[3]);   // y1 x1 z1

        const float dx = dxs[i], dy = dys[i], dz = dzs[i];
        const float w00 = dy * dx,          w01 = dy * (1.0f - dx);
        const float w10 = (1.0f - dy) * dx, w11 = (1.0f - dy) * (1.0f - dx);
        const float wz0 = dz, wz1 = 1.0f - dz;

        const float a0 = w00 * f0.x + w01 * f2.x + w10 * f4.x + w11 * f6.x;  // z0, c0
        const float b0 = w00 * f0.y + w01 * f2.y + w10 * f4.y + w11 * f6.y;  // z0, c1
        const float a1 = w00 * f1.x + w01 * f3.x + w10 * f5.x + w11 * f7.x;  // z1, c0
        const float b1 = w00 * f1.y + w01 * f3.y + w10 * f5.y + w11 * f7.y;  // z1, c1

        res[2 * i + 0] = wz0 * a0 + wz1 * a1;
        res[2 * i + 1] = wz0 * b0 + wz1 * b1;
    }

    nfloat4* __restrict__ o4 = reinterpret_cast<nfloat4*>(out);
    const nfloat4 r0 = {res[0], res[1], res[2], res[3]};
    const nfloat4 r1 = {res[4], res[5], res[6], res[7]};
    __builtin_nontemporal_store(r0, &o4[2 * t + 0]);
    __builtin_nontemporal_store(r1, &o4[2 * t + 1]);
}

// ---------------- fallback (direct fp32 path, both batches) ----------------
__global__ __launch_bounds__(BLOCK)
void TrilinearSampler_34059090658011_kernel(const float* __restrict__ im,
                                            const float* __restrict__ coords,
                                            float* __restrict__ out) {
    const int t = blockIdx.x * BLOCK + threadIdx.x;

    const float4* __restrict__ c4 = reinterpret_cast<const float4*>(coords);
    const float4 ca = c4[3 * t + 0];
    const float4 cb = c4[3 * t + 1];
    const float4 cc = c4[3 * t + 2];

    const int b = (t * PTS_PER_THREAD) >> 21;
    const char* __restrict__ imb =
        reinterpret_cast<const char*>(im) + (size_t)b * (size_t)Npts * 8u;

    const float ys[4] = {ca.x, ca.w, cb.z, cc.y};
    const float xs[4] = {ca.y, cb.x, cb.w, cc.z};
    const float zs[4] = {ca.z, cb.y, cc.x, cc.w};

    int   off[16];
    float w00[4], w01[4], w10[4], w11[4], wz0[4], wz1[4];
#pragma unroll
    for (int i = 0; i < 4; ++i) {
        const float x = xs[i] + 1.0f;
        const float y = ys[i] + 1.0f;
        const float z = zs[i] + 1.0f;
        const int x0 = (int)floorf(x);
        const int y0 = (int)floorf(y);
        const int z0 = (int)floorf(z);
        const float dx = (float)(x0 + 1) - x;
        const float dy = (float)(y0 + 1) - y;
        const float dz = (float)(z0 + 1) - z;
        const int ix0 = ::min(::max(x0 - 1, 0), Wc - 2);
        const int iy0 = ::min(::max(y0 - 1, 0), Hc - 2);
        const int izb = ::min(::max(z0 - 1, 0), Dc - 2);
        w00[i] = dx * dy;
        w01[i] = dx * (1.0f - dy);
        w10[i] = (1.0f - dx) * dy;
        w11[i] = (1.0f - dx) * (1.0f - dy);
        wz0[i] = dz;
        wz1[i] = 1.0f - dz;
        const int r00 = ((iy0 * Wc + ix0) * Dc + izb) * 8;
        off[4 * i + 0] = r00;
        off[4 * i + 1] = r00 + Wc * Dc * 8;
        off[4 * i + 2] = r00 + Dc * 8;
        off[4 * i + 3] = r00 + (Wc + 1) * Dc * 8;
    }

    f4u g[16];
#pragma unroll
    for (int j = 0; j < 16; ++j)
        g[j] = *reinterpret_cast<const f4u*>(imb + off[j]);

    float res[8];
#pragma unroll
    for (int i = 0; i < 4; ++i) {
        const f4u g00 = g[4 * i + 0];
        const f4u g01 = g[4 * i + 1];
        const f4u g10 = g[4 * i + 2];
        const f4u g11 = g[4 * i + 3];
        const float az0c0 = w00[i] * g00.x + w01[i] * g01.x + w10[i] * g10.x + w11[i] * g11.x;
        const float az0c1 = w00[i] * g00.y + w01[i] * g01.y + w10[i] * g10.y + w11[i] * g11.y;
        const float az1c0 = w00[i] * g00.z + w01[i] * g01.z + w10[i] * g10.z + w11[i] * g11.z;
        const float az1c1 = w00[i] * g00.w + w01[i] * g01.w + w10[i] * g10.w + w11[i] * g11.w;
        res[2 * i + 0] = wz0[i] * az0c0 + wz1[i] * az1c0;
        res[2 * i + 1] = wz0[i] * az0c1 + wz1[i] * az1c1;
    }

    float4* __restrict__ o4 = reinterpret_cast<float4*>(out);
    o4[2 * t + 0] = make_float4(res[0], res[1], res[2], res[3]);
    o4[2 * t + 1] = make_float4(res[4], res[5], res[6], res[7]);
}

extern "C" void kernel_launch(void* const* d_in, const int* in_sizes, int n_in,
                              void* d_out, int out_size, void* d_ws, size_t ws_size,
                              hipStream_t stream) {
    const float* im     = (const float*)d_in[0];
    const float* coords = (const float*)d_in[1];
    float* out          = (float*)d_out;

    if (ws_size >= REC_BYTES) {
        nfloat4* rec = (nfloat4*)d_ws;
        TrilinearSampler_34059090658011_repack<<<dim3(NCHUNKS / BLOCK), dim3(BLOCK), 0, stream>>>(im, rec);
        TrilinearSampler_34059090658011_sample<<<dim3(NTHREADS / BLOCK), dim3(BLOCK), 0, stream>>>(rec, coords, out);
    } else {
        TrilinearSampler_34059090658011_kernel<<<dim3(NTHREADS / BLOCK), dim3(BLOCK), 0, stream>>>(im, coords, out);
    }
}

// Round 3
// 213.153 us; speedup vs baseline: 1.0265x; 1.0135x over previous
//
#include <hip/hip_runtime.h>
#include <hip/hip_fp16.h>

// Trilinear sampler: im [B,H,W,D,C] f32, coords [B,N,3] f32 (y,x,z), out [B,N,C] f32.
// B=2, H=W=D=128, C=2, N=H*W*D.
//
// R10 post-mortem: nt->plain rec store = only -3us on sample (92->89); FETCH
//   invariant 280MB at 3.6 TB/s. Conclusion: 3.6 TB/s IS the random 64B-line
//   service ceiling; sample is floored (1 line/point, L2 already captures the
//   birthday-collision sharing: 230MB rec fetch < 268MB worst case).
// R11 (this round): 2D-tiled repack. Old repack staged 4 rows per z-row block
//   -> im read 4x = 134MB. New: block = 4x4 (y,x) cell tile x 128 z, stages
//   5x5=25 rows (25.6KB LDS) once; read amp 25/16 = 1.56x -> 52MB. Assemble
//   emits 16 coalesced 4KB store bursts (chunk-in-row == tid, as R8).
//   Record content/layout/clamps and sample pass byte-identical.
//   Predict: repack -10..16us if read-bound -> total ~200-206us; if <3us,
//   repack is at its 134MB-write floor and the structure is done.

constexpr int Hc = 128, Wc = 128, Dc = 128;
constexpr int Npts = Hc * Wc * Dc;                 // 2^21 points per batch
constexpr int CELLS = 1 << 21;                     // 128^3 cell records per batch
constexpr size_t REC_BYTES = (size_t)2 * CELLS * 32;   // 134,217,728 (both batches)
constexpr int PTS_PER_THREAD = 4;
constexpr int NTHREADS = 2 * Npts / PTS_PER_THREAD;
constexpr int BLOCK = 256;

typedef float nfloat4 __attribute__((ext_vector_type(4)));   // native vec for nt builtins

// 16-byte payload with only 8-byte alignment guarantee (fallback path)
struct __attribute__((packed, aligned(8))) f4u { float x, y, z, w; };

// ---------------- repack: im (fp32) -> per-cell 2x2x2x2ch fp16 records ----------------
// record layout (32B): half0 = y plane [x z, x z+1, x1 z, x1 z+1],
//                      half1 = y1 plane [same], each half = (c0,c1).
// R11 block = 4x4 (y,x) cells x full z: stage 5x5 rows, emit 16 x 4KB bursts.
__global__ __launch_bounds__(BLOCK)
void TrilinearSampler_34059090658011_repack(const float* __restrict__ im,
                                            nfloat4* __restrict__ rec) {
    __shared__ __align__(16) float2 srow[25][128];         // 5x5 rows (y-major), 25.6 KB

    const int tid = threadIdx.x;
    const int bid = blockIdx.x;                            // 2048 blocks: b(1) x ty(5b) x tx(5b)
    const int b   = bid >> 10;
    const int ty4 = ((bid >> 5) & 31) << 2;                // tile origin y
    const int tx4 = (bid & 31) << 2;                       // tile origin x

    const float* __restrict__ imb = im + ((size_t)b << 22);   // 2^21 cells * 2ch floats

    // ---- stage: 25 rows x 64 x 16B pieces = 1600 loads, coalesced per row ----
    for (int p = tid; p < 1600; p += BLOCK) {
        const int u_ = p >> 6;                             // row slot 0..24
        const int q  = p & 63;                             // 16B piece within row
        const int ry = (u_ * 13) >> 6;                     // u_/5
        const int rx = u_ - ry * 5;
        const int gy = ::min(ty4 + ry, 127);               // clamp = border replicate
        const int gx = ::min(tx4 + rx, 127);
        const nfloat4 v = *reinterpret_cast<const nfloat4*>(
            imb + ((size_t)(gy * 128 + gx) << 8) + (q << 2));
        reinterpret_cast<nfloat4*>(srow)[u_ * 64 + q] = v;
    }
    __syncthreads();

    // ---- assemble: per cell, 256 threads emit one contiguous 4KB chunk run ----
    const int h  = tid & 1;                                // 0: y plane, 1: y1 plane
    const int z  = tid >> 1;                               // cell z
    const int zb = ::min(z, 126);                          // z=127 cell never sampled
#pragma unroll
    for (int cc = 0; cc < 16; ++cc) {
        const int yy = cc >> 2, xx = cc & 3;
        const int r0 = (yy + h) * 5 + xx;                  // (y+h, x); +1 -> (y+h, x1)
        const float2 a0 = srow[r0][zb],     a1 = srow[r0][zb + 1];
        const float2 b0 = srow[r0 + 1][zb], b1 = srow[r0 + 1][zb + 1];

        union { __half2 hh[4]; nfloat4 f; } u;
        u.hh[0] = __floats2half2_rn(a0.x, a0.y);           // (yh, x,  z)
        u.hh[1] = __floats2half2_rn(a1.x, a1.y);           // (yh, x,  z+1)
        u.hh[2] = __floats2half2_rn(b0.x, b0.y);           // (yh, x1, z)
        u.hh[3] = __floats2half2_rn(b1.x, b1.y);           // (yh, x1, z+1)

        const int gy = ty4 + yy, gx = tx4 + xx;
        const size_t rowbase = ((size_t)b << 14) + (size_t)(gy << 7) + gx;
        // chunk id within row == tid -> lane i stores base+16*i: full-line stream
        rec[rowbase * 256 + tid] = u.f;
    }
}

// ---------------- sample pass: one 32B record (one 64B line) per point ----------------
__global__ __launch_bounds__(BLOCK)
void TrilinearSampler_34059090658011_sample(const nfloat4* __restrict__ rec,
                                            const float* __restrict__ coords,
                                            float* __restrict__ out) {
    const int t = blockIdx.x * BLOCK + threadIdx.x;        // one thread = 4 points

    const nfloat4* __restrict__ c4 = reinterpret_cast<const nfloat4*>(coords);
    const nfloat4 ca = __builtin_nontemporal_load(&c4[3 * t + 0]);
    const nfloat4 cb = __builtin_nontemporal_load(&c4[3 * t + 1]);
    const nfloat4 cc = __builtin_nontemporal_load(&c4[3 * t + 2]);

    const int b = (t * PTS_PER_THREAD) >> 21;              // wave-uniform
    const nfloat4* __restrict__ rb = rec + ((size_t)b << 22);   // CELLS*2 nfloat4/batch

    const float ys[4] = {ca.x, ca.w, cb.z, cc.y};
    const float xs[4] = {ca.y, cb.x, cb.w, cc.z};
    const float zs[4] = {ca.z, cb.y, cc.x, cc.w};

    // phase 1: cells + weights
    int   cidx[4];
    float dxs[4], dys[4], dzs[4];
#pragma unroll
    for (int i = 0; i < 4; ++i) {
        const float x = xs[i] + 1.0f;
        const float y = ys[i] + 1.0f;
        const float z = zs[i] + 1.0f;
        const int x0 = (int)floorf(x);
        const int y0 = (int)floorf(y);
        const int z0 = (int)floorf(z);
        dxs[i] = (float)(x0 + 1) - x;                      // interior guaranteed
        dys[i] = (float)(y0 + 1) - y;
        dzs[i] = (float)(z0 + 1) - z;
        const int ix0 = ::min(::max(x0 - 1, 0), Wc - 2);
        const int iy0 = ::min(::max(y0 - 1, 0), Hc - 2);
        const int izb = ::min(::max(z0 - 1, 0), Dc - 2);
        cidx[i] = ((iy0 << 7) | ix0) << 7 | izb;
    }

    // phase 2: 8 loads (2 per point, same 64B line)
    nfloat4 lo[4], hi[4];
#pragma unroll
    for (int i = 0; i < 4; ++i) {
        lo[i] = rb[(size_t)cidx[i] * 2 + 0];
        hi[i] = rb[(size_t)cidx[i] * 2 + 1];
    }

    // phase 3: combine
    float res[8];
#pragma unroll
    for (int i = 0; i < 4; ++i) {
        const __half2* h = reinterpret_cast<const __half2*>(&lo[i]);   // y0 plane
        const __half2* g = reinterpret_cast<const __half2*>(&hi[i]);   // y1 plane
        const float2 f0 = __half22float2(h[0]);   // y0 x0 z0
        const float2 f1 = __half22float2(h[1]);   // y0 x0 z1
        const float2 f2 = __half22float2(h[2]);   // y0 x1 z0
        const float2 f3 = __half22float2(h[3]);   // y0 x1 z1
        const float2 f4 = __half22float2(g[0]);   // y1 x0 z0
        const float2 f5 = __half22float2(g[1]);   // y1 x0 z1
        const float2 f6 = __half22float2(g[2]);   // y1 x1 z0
        const float2 f7 = __half22float2(g[3]);   // y1 x1 z1

        const float dx = dxs[i], dy = dys[i], dz = dzs[i];
        const float w00 = dy * dx,          w01 = dy * (1.0f - dx);
        const float w10 = (1.0f - dy) * dx, w11 = (1.0f - dy) * (1.0f - dx);
        const float wz0 = dz, wz1 = 1.0f - dz;

        const float a0 = w00 * f0.x + w01 * f2.x + w10 * f4.x + w11 * f6.x;  // z0, c0
        const float b0 = w00 * f0.y + w01 * f2.y + w10 * f4.y + w11 * f6.y;  // z0, c1
        const float a1 = w00 * f1.x + w01 * f3.x + w10 * f5.x + w11 * f7.x;  // z1, c0
        const float b1 = w00 * f1.y + w01 * f3.y + w10 * f5.y + w11 * f7.y;  // z1, c1

        res[2 * i + 0] = wz0 * a0 + wz1 * a1;
        res[2 * i + 1] = wz0 * b0 + wz1 * b1;
    }

    nfloat4* __restrict__ o4 = reinterpret_cast<nfloat4*>(out);
    const nfloat4 r0 = {res[0], res[1], res[2], res[3]};
    const nfloat4 r1 = {res[4], res[5], res[6], res[7]};
    __builtin_nontemporal_store(r0, &o4[2 * t + 0]);
    __builtin_nontemporal_store(r1, &o4[2 * t + 1]);
}

// ---------------- fallback (direct fp32 path, both batches) ----------------
__global__ __launch_bounds__(BLOCK)
void TrilinearSampler_34059090658011_kernel(const float* __restrict__ im,
                                            const float* __restrict__ coords,
                                            float* __restrict__ out) {
    const int t = blockIdx.x * BLOCK + threadIdx.x;

    const float4* __restrict__ c4 = reinterpret_cast<const float4*>(coords);
    const float4 ca = c4[3 * t + 0];
    const float4 cb = c4[3 * t + 1];
    const float4 cc = c4[3 * t + 2];

    const int b = (t * PTS_PER_THREAD) >> 21;
    const char* __restrict__ imb =
        reinterpret_cast<const char*>(im) + (size_t)b * (size_t)Npts * 8u;

    const float ys[4] = {ca.x, ca.w, cb.z, cc.y};
    const float xs[4] = {ca.y, cb.x, cb.w, cc.z};
    const float zs[4] = {ca.z, cb.y, cc.x, cc.w};

    int   off[16];
    float w00[4], w01[4], w10[4], w11[4], wz0[4], wz1[4];
#pragma unroll
    for (int i = 0; i < 4; ++i) {
        const float x = xs[i] + 1.0f;
        const float y = ys[i] + 1.0f;
        const float z = zs[i] + 1.0f;
        const int x0 = (int)floorf(x);
        const int y0 = (int)floorf(y);
        const int z0 = (int)floorf(z);
        const float dx = (float)(x0 + 1) - x;
        const float dy = (float)(y0 + 1) - y;
        const float dz = (float)(z0 + 1) - z;
        const int ix0 = ::min(::max(x0 - 1, 0), Wc - 2);
        const int iy0 = ::min(::max(y0 - 1, 0), Hc - 2);
        const int izb = ::min(::max(z0 - 1, 0), Dc - 2);
        w00[i] = dx * dy;
        w01[i] = dx * (1.0f - dy);
        w10[i] = (1.0f - dx) * dy;
        w11[i] = (1.0f - dx) * (1.0f - dy);
        wz0[i] = dz;
        wz1[i] = 1.0f - dz;
        const int r00 = ((iy0 * Wc + ix0) * Dc + izb) * 8;
        off[4 * i + 0] = r00;
        off[4 * i + 1] = r00 + Wc * Dc * 8;
        off[4 * i + 2] = r00 + Dc * 8;
        off[4 * i + 3] = r00 + (Wc + 1) * Dc * 8;
    }

    f4u g[16];
#pragma unroll
    for (int j = 0; j < 16; ++j)
        g[j] = *reinterpret_cast<const f4u*>(imb + off[j]);

    float res[8];
#pragma unroll
    for (int i = 0; i < 4; ++i) {
        const f4u g00 = g[4 * i + 0];
        const f4u g01 = g[4 * i + 1];
        const f4u g10 = g[4 * i + 2];
        const f4u g11 = g[4 * i + 3];
        const float az0c0 = w00[i] * g00.x + w01[i] * g01.x + w10[i] * g10.x + w11[i] * g11.x;
        const float az0c1 = w00[i] * g00.y + w01[i] * g01.y + w10[i] * g10.y + w11[i] * g11.y;
        const float az1c0 = w00[i] * g00.z + w01[i] * g01.z + w10[i] * g10.z + w11[i] * g11.z;
        const float az1c1 = w00[i] * g00.w + w01[i] * g01.w + w10[i] * g10.w + w11[i] * g11.w;
        res[2 * i + 0] = wz0[i] * az0c0 + wz1[i] * az1c0;
        res[2 * i + 1] = wz0[i] * az0c1 + wz1[i] * az1c1;
    }

    float4* __restrict__ o4 = reinterpret_cast<float4*>(out);
    o4[2 * t + 0] = make_float4(res[0], res[1], res[2], res[3]);
    o4[2 * t + 1] = make_float4(res[4], res[5], res[6], res[7]);
}

extern "C" void kernel_launch(void* const* d_in, const int* in_sizes, int n_in,
                              void* d_out, int out_size, void* d_ws, size_t ws_size,
                              hipStream_t stream) {
    const float* im     = (const float*)d_in[0];
    const float* coords = (const float*)d_in[1];
    float* out          = (float*)d_out;

    if (ws_size >= REC_BYTES) {
        nfloat4* rec = (nfloat4*)d_ws;
        // 2 batches x 32x32 tiles of 4x4 cells
        TrilinearSampler_34059090658011_repack<<<dim3(2048), dim3(BLOCK), 0, stream>>>(im, rec);
        TrilinearSampler_34059090658011_sample<<<dim3(NTHREADS / BLOCK), dim3(BLOCK), 0, stream>>>(rec, coords, out);
    } else {
        TrilinearSampler_34059090658011_kernel<<<dim3(NTHREADS / BLOCK), dim3(BLOCK), 0, stream>>>(im, coords, out);
    }
}

// Round 4
// 205.761 us; speedup vs baseline: 1.0634x; 1.0359x over previous
//
#include <hip/hip_runtime.h>
#include <hip/hip_fp16.h>

// Trilinear sampler: im [B,H,W,D,C] f32, coords [B,N,3] f32 (y,x,z), out [B,N,C] f32.
// B=2, H=W=D=128, C=2, N=H*W*D.
//
// R11 post-mortem: tiled repack only -2.9us -> repack is at its WRITE floor
//   (134MB rec); the 4x im re-read was L2-absorbed. Sample invariant:
//   88.3us, FETCH 280MB @ 3.6 TB/s random-line ceiling.
// R12 (this round): z-plane records. Old: 32B record per cell (8 corners,
//   z-duplicated 2x). New: 16B record per (cy,cx,z) = 4 (y,x)-corners x 2ch
//   fp16 at ONE z. A cell reads records cidx and cidx+1 (contiguous 32B, same
//   2 dwordx4 loads). rec 134MB -> 67MB: repack write floor halves, sample
//   unique-line set halves (33.5MB/batch ~ L2-aggregate), ~4 pts/line sharing.
//   Predict: sample FETCH 280 -> ~170-210MB, dur 88 -> 62-75us; repack
//   -10-15us; total 213 -> ~180-195us. absmax unchanged (same fp16 math).

constexpr int Hc = 128, Wc = 128, Dc = 128;
constexpr int Npts = Hc * Wc * Dc;                 // 2^21 points per batch
constexpr int CELLS = 1 << 21;                     // 128^3 records per batch (16B each)
constexpr size_t REC_BYTES = (size_t)2 * CELLS * 16;   // 67,108,864 (both batches)
constexpr int PTS_PER_THREAD = 4;
constexpr int NTHREADS = 2 * Npts / PTS_PER_THREAD;
constexpr int BLOCK = 256;

typedef float nfloat4 __attribute__((ext_vector_type(4)));   // native vec for nt builtins

// 16-byte payload with only 8-byte alignment guarantee (fallback path)
struct __attribute__((packed, aligned(8))) f4u { float x, y, z, w; };

// ---------------- repack: im (fp32) -> per-(cy,cx,z) 4-corner fp16 records ----------------
// record layout (16B): hh[0]=(y,x) hh[1]=(y,x1) hh[2]=(y1,x) hh[3]=(y1,x1), each (c0,c1).
// Block = 4x4 (cy,cx) tile x full z: stage 5x5 voxel rows, emit 16 x 2KB column bursts.
__global__ __launch_bounds__(BLOCK)
void TrilinearSampler_34059090658011_repack(const float* __restrict__ im,
                                            nfloat4* __restrict__ rec) {
    __shared__ __align__(16) float2 srow[25][128];         // 5x5 rows (y-major), 25.6 KB

    const int tid = threadIdx.x;
    const int bid = blockIdx.x;                            // 2048 blocks: b(1) x ty(5b) x tx(5b)
    const int b   = bid >> 10;
    const int ty4 = ((bid >> 5) & 31) << 2;                // tile origin y
    const int tx4 = (bid & 31) << 2;                       // tile origin x

    const float* __restrict__ imb = im + ((size_t)b << 22);   // 2^21 voxels * 2ch floats

    // ---- stage: 25 rows x 64 x 16B pieces = 1600 loads, coalesced per row ----
    for (int p = tid; p < 1600; p += BLOCK) {
        const int u_ = p >> 6;                             // row slot 0..24
        const int q  = p & 63;                             // 16B piece within row
        const int ry = (u_ * 13) >> 6;                     // u_/5
        const int rx = u_ - ry * 5;
        const int gy = ::min(ty4 + ry, 127);               // clamp = border replicate
        const int gx = ::min(tx4 + rx, 127);
        const nfloat4 v = *reinterpret_cast<const nfloat4*>(
            imb + ((size_t)(gy * 128 + gx) << 8) + (q << 2));
        reinterpret_cast<nfloat4*>(srow)[u_ * 64 + q] = v;
    }
    __syncthreads();

    // ---- assemble: thread builds record (column cc, height z); 2 cols/iter ----
    const int z  = tid & 127;
    const int cp = tid >> 7;                               // column-pair member 0/1
#pragma unroll
    for (int k = 0; k < 8; ++k) {
        const int cc = k * 2 + cp;                         // 0..15
        const int yy = cc >> 2, xx = cc & 3;
        const int s00 = yy * 5 + xx;
        const float2 f0 = srow[s00][z];                    // (y,  x )
        const float2 f1 = srow[s00 + 1][z];                // (y,  x1)
        const float2 f2 = srow[s00 + 5][z];                // (y1, x )
        const float2 f3 = srow[s00 + 6][z];                // (y1, x1)

        union { __half2 hh[4]; nfloat4 f; } u;
        u.hh[0] = __floats2half2_rn(f0.x, f0.y);
        u.hh[1] = __floats2half2_rn(f1.x, f1.y);
        u.hh[2] = __floats2half2_rn(f2.x, f2.y);
        u.hh[3] = __floats2half2_rn(f3.x, f3.y);

        const int gy = ty4 + yy, gx = tx4 + xx;
        // column base contiguous in z: lanes 0..63 (z consecutive) = 1KB burst
        rec[((((size_t)b << 14) + (gy << 7) + gx) << 7) + z] = u.f;
    }
}

// ---------------- sample pass: two contiguous 16B records (32B) per point ----------------
__global__ __launch_bounds__(BLOCK)
void TrilinearSampler_34059090658011_sample(const nfloat4* __restrict__ rec,
                                            const float* __restrict__ coords,
                                            float* __restrict__ out) {
    const int t = blockIdx.x * BLOCK + threadIdx.x;        // one thread = 4 points

    const nfloat4* __restrict__ c4 = reinterpret_cast<const nfloat4*>(coords);
    const nfloat4 ca = __builtin_nontemporal_load(&c4[3 * t + 0]);
    const nfloat4 cb = __builtin_nontemporal_load(&c4[3 * t + 1]);
    const nfloat4 cc = __builtin_nontemporal_load(&c4[3 * t + 2]);

    const int b = (t * PTS_PER_THREAD) >> 21;              // wave-uniform
    const nfloat4* __restrict__ rb = rec + ((size_t)b << 21);   // CELLS records/batch

    const float ys[4] = {ca.x, ca.w, cb.z, cc.y};
    const float xs[4] = {ca.y, cb.x, cb.w, cc.z};
    const float zs[4] = {ca.z, cb.y, cc.x, cc.w};

    // phase 1: cells + weights
    int   cidx[4];
    float dxs[4], dys[4], dzs[4];
#pragma unroll
    for (int i = 0; i < 4; ++i) {
        const float x = xs[i] + 1.0f;
        const float y = ys[i] + 1.0f;
        const float z = zs[i] + 1.0f;
        const int x0 = (int)floorf(x);
        const int y0 = (int)floorf(y);
        const int z0 = (int)floorf(z);
        dxs[i] = (float)(x0 + 1) - x;                      // interior guaranteed
        dys[i] = (float)(y0 + 1) - y;
        dzs[i] = (float)(z0 + 1) - z;
        const int ix0 = ::min(::max(x0 - 1, 0), Wc - 2);
        const int iy0 = ::min(::max(y0 - 1, 0), Hc - 2);
        const int izb = ::min(::max(z0 - 1, 0), Dc - 2);
        cidx[i] = ((iy0 << 7) | ix0) << 7 | izb;
    }

    // phase 2: 8 loads (2 contiguous 16B records per point)
    nfloat4 lo[4], hi[4];
#pragma unroll
    for (int i = 0; i < 4; ++i) {
        lo[i] = rb[cidx[i]];                               // z0 plane
        hi[i] = rb[cidx[i] + 1];                           // z1 plane
    }

    // phase 3: combine
    float res[8];
#pragma unroll
    for (int i = 0; i < 4; ++i) {
        const __half2* h = reinterpret_cast<const __half2*>(&lo[i]);   // z0 plane
        const __half2* g = reinterpret_cast<const __half2*>(&hi[i]);   // z1 plane
        const float2 f0 = __half22float2(h[0]);   // z0 (y0,x0)
        const float2 f1 = __half22float2(h[1]);   // z0 (y0,x1)
        const float2 f2 = __half22float2(h[2]);   // z0 (y1,x0)
        const float2 f3 = __half22float2(h[3]);   // z0 (y1,x1)
        const float2 g0 = __half22float2(g[0]);   // z1 (y0,x0)
        const float2 g1 = __half22float2(g[1]);   // z1 (y0,x1)
        const float2 g2 = __half22float2(g[2]);   // z1 (y1,x0)
        const float2 g3 = __half22float2(g[3]);   // z1 (y1,x1)

        const float dx = dxs[i], dy = dys[i], dz = dzs[i];
        const float w00 = dy * dx,          w01 = dy * (1.0f - dx);
        const float w10 = (1.0f - dy) * dx, w11 = (1.0f - dy) * (1.0f - dx);
        const float wz0 = dz, wz1 = 1.0f - dz;

        const float a0 = w00 * f0.x + w01 * f1.x + w10 * f2.x + w11 * f3.x;  // z0, c0
        const float b0 = w00 * f0.y + w01 * f1.y + w10 * f2.y + w11 * f3.y;  // z0, c1
        const float a1 = w00 * g0.x + w01 * g1.x + w10 * g2.x + w11 * g3.x;  // z1, c0
        const float b1 = w00 * g0.y + w01 * g1.y + w10 * g2.y + w11 * g3.y;  // z1, c1

        res[2 * i + 0] = wz0 * a0 + wz1 * a1;
        res[2 * i + 1] = wz0 * b0 + wz1 * b1;
    }

    nfloat4* __restrict__ o4 = reinterpret_cast<nfloat4*>(out);
    const nfloat4 r0 = {res[0], res[1], res[2], res[3]};
    const nfloat4 r1 = {res[4], res[5], res[6], res[7]};
    __builtin_nontemporal_store(r0, &o4[2 * t + 0]);
    __builtin_nontemporal_store(r1, &o4[2 * t + 1]);
}

// ---------------- fallback (direct fp32 path, both batches) ----------------
__global__ __launch_bounds__(BLOCK)
void TrilinearSampler_34059090658011_kernel(const float* __restrict__ im,
                                            const float* __restrict__ coords,
                                            float* __restrict__ out) {
    const int t = blockIdx.x * BLOCK + threadIdx.x;

    const float4* __restrict__ c4 = reinterpret_cast<const float4*>(coords);
    const float4 ca = c4[3 * t + 0];
    const float4 cb = c4[3 * t + 1];
    const float4 cc = c4[3 * t + 2];

    const int b = (t * PTS_PER_THREAD) >> 21;
    const char* __restrict__ imb =
        reinterpret_cast<const char*>(im) + (size_t)b * (size_t)Npts * 8u;

    const float ys[4] = {ca.x, ca.w, cb.z, cc.y};
    const float xs[4] = {ca.y, cb.x, cb.w, cc.z};
    const float zs[4] = {ca.z, cb.y, cc.x, cc.w};

    int   off[16];
    float w00[4], w01[4], w10[4], w11[4], wz0[4], wz1[4];
#pragma unroll
    for (int i = 0; i < 4; ++i) {
        const float x = xs[i] + 1.0f;
        const float y = ys[i] + 1.0f;
        const float z = zs[i] + 1.0f;
        const int x0 = (int)floorf(x);
        const int y0 = (int)floorf(y);
        const int z0 = (int)floorf(z);
        const float dx = (float)(x0 + 1) - x;
        const float dy = (float)(y0 + 1) - y;
        const float dz = (float)(z0 + 1) - z;
        const int ix0 = ::min(::max(x0 - 1, 0), Wc - 2);
        const int iy0 = ::min(::max(y0 - 1, 0), Hc - 2);
        const int izb = ::min(::max(z0 - 1, 0), Dc - 2);
        w00[i] = dx * dy;
        w01[i] = dx * (1.0f - dy);
        w10[i] = (1.0f - dx) * dy;
        w11[i] = (1.0f - dx) * (1.0f - dy);
        wz0[i] = dz;
        wz1[i] = 1.0f - dz;
        const int r00 = ((iy0 * Wc + ix0) * Dc + izb) * 8;
        off[4 * i + 0] = r00;
        off[4 * i + 1] = r00 + Wc * Dc * 8;
        off[4 * i + 2] = r00 + Dc * 8;
        off[4 * i + 3] = r00 + (Wc + 1) * Dc * 8;
    }

    f4u g[16];
#pragma unroll
    for (int j = 0; j < 16; ++j)
        g[j] = *reinterpret_cast<const f4u*>(imb + off[j]);

    float res[8];
#pragma unroll
    for (int i = 0; i < 4; ++i) {
        const f4u g00 = g[4 * i + 0];
        const f4u g01 = g[4 * i + 1];
        const f4u g10 = g[4 * i + 2];
        const f4u g11 = g[4 * i + 3];
        const float az0c0 = w00[i] * g00.x + w01[i] * g01.x + w10[i] * g10.x + w11[i] * g11.x;
        const float az0c1 = w00[i] * g00.y + w01[i] * g01.y + w10[i] * g10.y + w11[i] * g11.y;
        const float az1c0 = w00[i] * g00.z + w01[i] * g01.z + w10[i] * g10.z + w11[i] * g11.z;
        const float az1c1 = w00[i] * g00.w + w01[i] * g01.w + w10[i] * g10.w + w11[i] * g11.w;
        res[2 * i + 0] = wz0[i] * az0c0 + wz1[i] * az1c0;
        res[2 * i + 1] = wz0[i] * az0c1 + wz1[i] * az1c1;
    }

    float4* __restrict__ o4 = reinterpret_cast<float4*>(out);
    o4[2 * t + 0] = make_float4(res[0], res[1], res[2], res[3]);
    o4[2 * t + 1] = make_float4(res[4], res[5], res[6], res[7]);
}

extern "C" void kernel_launch(void* const* d_in, const int* in_sizes, int n_in,
                              void* d_out, int out_size, void* d_ws, size_t ws_size,
                              hipStream_t stream) {
    const float* im     = (const float*)d_in[0];
    const float* coords = (const float*)d_in[1];
    float* out          = (float*)d_out;

    if (ws_size >= REC_BYTES) {
        nfloat4* rec = (nfloat4*)d_ws;
        // 2 batches x 32x32 tiles of 4x4 (cy,cx) columns
        TrilinearSampler_34059090658011_repack<<<dim3(2048), dim3(BLOCK), 0, stream>>>(im, rec);
        TrilinearSampler_34059090658011_sample<<<dim3(NTHREADS / BLOCK), dim3(BLOCK), 0, stream>>>(rec, coords, out);
    } else {
        TrilinearSampler_34059090658011_kernel<<<dim3(NTHREADS / BLOCK), dim3(BLOCK), 0, stream>>>(im, coords, out);
    }
}